// Round 1
// baseline (164.183 us; speedup 1.0000x reference)
//
#include <hip/hip_runtime.h>
#include <hip/hip_bf16.h>
#include <math.h>

// y[b,l,d] = x[b,l,d] * softplus((x@W1+b1)[b,l,d]) * sum_n((x@W2+b2)*(x@W3+b3))[b,l,n]

#define GLB(p) ((const __attribute__((address_space(1))) void*)(p))
#define LDSP(p) ((__attribute__((address_space(3))) void*)(p))

namespace {

constexpr int Dd   = 1024;   // feature dim
constexpr int ROWS = 8192;   // BS*L
constexpr int RPB  = 8;      // rows per block in prep_x

typedef __bf16 bf16x8 __attribute__((ext_vector_type(8)));
typedef float  floatx4 __attribute__((ext_vector_type(4)));

__device__ __forceinline__ float softplus_f(float v) {
    // logaddexp(v, 0) = max(v,0) + log1p(exp(-|v|)) — stable both directions
    return fmaxf(v, 0.0f) + log1pf(expf(-fabsf(v)));
}

// ---------------------------------------------------------------------------
// Kernel 1: per 8 rows — convert x to bf16 (for MFMA) and compute
// s[row] = sum_n (x.W2_n + b2_n)(x.W3_n + b3_n) in fp32.
// ---------------------------------------------------------------------------
__global__ __launch_bounds__(256) void prep_x_kernel(
    const float* __restrict__ X,
    const float* __restrict__ W2, const float* __restrict__ b2,
    const float* __restrict__ W3, const float* __restrict__ b3,
    __bf16* __restrict__ Xb, float* __restrict__ Sv)
{
    __shared__ float xrow[RPB][Dd];
    __shared__ float part[8][2][16][RPB];   // [dgroup][which][n][row]
    __shared__ float bc[2][16][RPB];        // [which][n][row]
    const int t  = threadIdx.x;
    const int r0 = blockIdx.x * RPB;

    // Phase 1: load 8 rows, stash fp32 in LDS, write bf16 copy to workspace.
    for (int i = 0; i < RPB; ++i) {
        const float4 v = *(const float4*)&X[(size_t)(r0 + i) * Dd + t * 4];
        xrow[i][t * 4 + 0] = v.x; xrow[i][t * 4 + 1] = v.y;
        xrow[i][t * 4 + 2] = v.z; xrow[i][t * 4 + 3] = v.w;
        union { __bf16 h[4]; ushort4 u; } cv;
        cv.h[0] = (__bf16)v.x; cv.h[1] = (__bf16)v.y;
        cv.h[2] = (__bf16)v.z; cv.h[3] = (__bf16)v.w;
        *(ushort4*)&Xb[(size_t)(r0 + i) * Dd + t * 4] = cv.u;
    }
    __syncthreads();

    // Phase 2: thread = (dgroup g, which, n); accumulate over its 128-d slice
    // for all 8 rows. W2/W3 element loaded once, reused across 8 rows.
    {
        const int n     = t & 15;
        const int which = (t >> 4) & 1;
        const int g     = t >> 5;
        const float* __restrict__ W = which ? W3 : W2;
        float accv[RPB];
        #pragma unroll
        for (int i = 0; i < RPB; ++i) accv[i] = 0.0f;
        const int dbase = g * 128;
        for (int dd = 0; dd < 128; ++dd) {
            const float wv = W[(dbase + dd) * 16 + n];
            #pragma unroll
            for (int i = 0; i < RPB; ++i) accv[i] += xrow[i][dbase + dd] * wv;
        }
        #pragma unroll
        for (int i = 0; i < RPB; ++i) part[g][which][n][i] = accv[i];
    }
    __syncthreads();

    // Phase 3: 256 threads = 2*16*8 (which,n,row) combos — reduce over dgroups.
    {
        const int rr = t & 7, nn = (t >> 3) & 15, ww = t >> 7;
        float s = (ww ? b3 : b2)[nn];
        #pragma unroll
        for (int gg = 0; gg < 8; ++gg) s += part[gg][ww][nn][rr];
        bc[ww][nn][rr] = s;
    }
    __syncthreads();

    if (t < RPB) {
        float s = 0.0f;
        #pragma unroll
        for (int nn = 0; nn < 16; ++nn) s += bc[0][nn][t] * bc[1][nn][t];
        Sv[r0 + t] = s;
    }
}

// ---------------------------------------------------------------------------
// Kernel 2: W1 (k-major, [k][n]) -> W1t bf16 ([n][k]) so GEMM B-fragments are
// k-contiguous in LDS. 64x64 tiles via padded LDS.
// ---------------------------------------------------------------------------
__global__ __launch_bounds__(256) void prep_w1_kernel(
    const float* __restrict__ W1, __bf16* __restrict__ W1t)
{
    __shared__ __bf16 tile[64][66];  // pad 2 -> 132B row stride, conflict-free
    const int t  = threadIdx.x;
    const int bi = blockIdx.x >> 4;   // k tile
    const int bj = blockIdx.x & 15;   // n tile
    const int c  = t & 63, r4 = t >> 6;
    #pragma unroll
    for (int i = 0; i < 16; ++i) {
        const int r = i * 4 + r4;     // k_local
        tile[r][c] = (__bf16)W1[(size_t)(bi * 64 + r) * Dd + bj * 64 + c];
    }
    __syncthreads();
    #pragma unroll
    for (int i = 0; i < 16; ++i) {
        const int r = i * 4 + r4;     // n_local
        W1t[(size_t)(bj * 64 + r) * Dd + bi * 64 + c] = tile[c][r];
    }
}

// ---------------------------------------------------------------------------
// Kernel 3: bf16 MFMA GEMM (m97-style 128x128xBK32) with fused epilogue:
// y = x * softplus(acc + b1) * s[row]
// ---------------------------------------------------------------------------
__global__ __launch_bounds__(256, 2) void gemm_kernel(
    const __bf16* __restrict__ Xb, const __bf16* __restrict__ W1t,
    const float* __restrict__ Sv, const float* __restrict__ Xf,
    const float* __restrict__ b1, float* __restrict__ Y)
{
    // A tile [128][32] bf16 at elem 0; B tile [128 n][32 k] bf16 at elem 4096.
    __shared__ __attribute__((aligned(16))) __bf16 lds[8192];
    const int t    = threadIdx.x;
    const int lane = t & 63;
    const int w    = t >> 6;
    const int wm   = w & 1, wn = w >> 1;
    const int cb   = blockIdx.x & 7, rb = blockIdx.x >> 3;
    const int row0 = rb * 128, col0 = cb * 128;
    const int quad = lane >> 4;
    const int l15  = lane & 15;

    floatx4 acc[4][4] = {};

    // staging: thread t loads 16B at (row0 + r*64 + t/4, k0 + (t%4)*8)
    const int srow  = t >> 2;
    const int skoff = (t & 3) * 8;
    const __bf16* gA = Xb  + (size_t)(row0 + srow) * Dd + skoff;
    const __bf16* gB = W1t + (size_t)(col0 + srow) * Dd + skoff;
    const int ldsA0 = w * 512;          // wave-uniform, elem units (+r*2048)
    const int ldsB0 = 4096 + w * 512;

    for (int k0 = 0; k0 < Dd; k0 += 32) {
        #pragma unroll
        for (int r = 0; r < 2; ++r) {
            __builtin_amdgcn_global_load_lds(GLB(gA + (size_t)(r * 64) * Dd + k0),
                                             LDSP(&lds[ldsA0 + r * 2048]), 16, 0, 0);
            __builtin_amdgcn_global_load_lds(GLB(gB + (size_t)(r * 64) * Dd + k0),
                                             LDSP(&lds[ldsB0 + r * 2048]), 16, 0, 0);
        }
        __syncthreads();   // drains vmcnt before compute

        bf16x8 af[4], bb[4];
        #pragma unroll
        for (int mt = 0; mt < 4; ++mt)
            af[mt] = *(const bf16x8*)&lds[(wm * 64 + mt * 16 + l15) * 32 + quad * 8];
        #pragma unroll
        for (int nt = 0; nt < 4; ++nt)
            bb[nt] = *(const bf16x8*)&lds[4096 + (wn * 64 + nt * 16 + l15) * 32 + quad * 8];

        #pragma unroll
        for (int mt = 0; mt < 4; ++mt)
            #pragma unroll
            for (int nt = 0; nt < 4; ++nt)
                acc[mt][nt] = __builtin_amdgcn_mfma_f32_16x16x32_bf16(
                    af[mt], bb[nt], acc[mt][nt], 0, 0, 0);
        __syncthreads();   // before next tile overwrites LDS
    }

    // Epilogue. C/D layout: col = lane&15, row = quad*4 + reg.
    #pragma unroll
    for (int nt = 0; nt < 4; ++nt) {
        const int col = col0 + wn * 64 + nt * 16 + l15;
        const float bias = b1[col];
        #pragma unroll
        for (int mt = 0; mt < 4; ++mt) {
            const int rbase = row0 + wm * 64 + mt * 16 + quad * 4;
            #pragma unroll
            for (int r = 0; r < 4; ++r) {
                const int row = rbase + r;
                const float v  = acc[mt][nt][r] + bias;
                const float sp = softplus_f(v);
                Y[(size_t)row * Dd + col] = Xf[(size_t)row * Dd + col] * sp * Sv[row];
            }
        }
    }
}

} // namespace

extern "C" void kernel_launch(void* const* d_in, const int* in_sizes, int n_in,
                              void* d_out, int out_size, void* d_ws, size_t ws_size,
                              hipStream_t stream)
{
    const float* X  = (const float*)d_in[0];
    const float* W1 = (const float*)d_in[1];
    const float* b1 = (const float*)d_in[2];
    const float* W2 = (const float*)d_in[3];
    const float* b2 = (const float*)d_in[4];
    const float* W3 = (const float*)d_in[5];
    const float* b3 = (const float*)d_in[6];
    // d_in[7] = A is dead code in the reference.
    float* Y = (float*)d_out;

    // workspace layout: Xb (16 MB bf16) | W1t (2 MB bf16) | Sv (32 KB fp32)
    __bf16* Xb  = (__bf16*)d_ws;
    __bf16* W1t = (__bf16*)((char*)d_ws + (size_t)ROWS * Dd * 2);
    float*  Sv  = (float*)((char*)d_ws + (size_t)ROWS * Dd * 2 + (size_t)Dd * Dd * 2);

    hipLaunchKernelGGL(prep_x_kernel, dim3(ROWS / RPB), dim3(256), 0, stream,
                       X, W2, b2, W3, b3, Xb, Sv);
    hipLaunchKernelGGL(prep_w1_kernel, dim3(256), dim3(256), 0, stream, W1, W1t);
    hipLaunchKernelGGL(gemm_kernel, dim3((ROWS / 128) * (Dd / 128)), dim3(256), 0, stream,
                       Xb, W1t, Sv, X, b1, Y);
}

// Round 2
// 151.558 us; speedup vs baseline: 1.0833x; 1.0833x over previous
//
#include <hip/hip_runtime.h>
#include <hip/hip_bf16.h>
#include <math.h>

// y[b,l,d] = x[b,l,d] * softplus((x@W1+b1)[b,l,d]) * sum_n((x@W2+b2)*(x@W3+b3))[b,l,n]

#define GLB(p) ((const __attribute__((address_space(1))) void*)(p))
#define LDSP(p) ((__attribute__((address_space(3))) void*)(p))

namespace {

constexpr int Dd   = 1024;
constexpr int ROWS = 8192;

typedef __bf16 bf16x8 __attribute__((ext_vector_type(8)));
typedef float  floatx4 __attribute__((ext_vector_type(4)));

__device__ __forceinline__ float bf_lo(unsigned u) {
    union { unsigned q; float f; } c; c.q = u << 16; return c.f;
}
__device__ __forceinline__ float bf_hi(unsigned u) {
    union { unsigned q; float f; } c; c.q = u & 0xffff0000u; return c.f;
}
__device__ __forceinline__ unsigned short bf16u(float f) {
    union { __bf16 h; unsigned short u; } c; c.h = (__bf16)f; return c.u;
}
__device__ __forceinline__ float softplus_fast(float v) {
    // log(1+e^v) via HW v_exp/v_log; select covers overflow (v>~88 -> inf)
    float l = __logf(1.0f + __expf(v));
    return v > 15.0f ? v : l;
}

// ---------------------------------------------------------------------------
// Kernel 1: convert x -> bf16 Xb and compute s[row] = sum_n (x.W2+b2)(x.W3+b3).
// Block: 256 threads = 16 row-groups (2 rows each) x 16 k-lanes; 32 rows/block.
// W2|W3 staged to LDS as bf16 with 16B-slot XOR swizzle (4-way max conflict).
// ---------------------------------------------------------------------------
__global__ __launch_bounds__(256, 2) void prep_x_kernel(
    const float* __restrict__ X,
    const float* __restrict__ W2, const float* __restrict__ b2,
    const float* __restrict__ W3, const float* __restrict__ b3,
    __bf16* __restrict__ Xb, float* __restrict__ Sv)
{
    __shared__ __bf16 Wl[512][32];   // 32 KB, holds one K-half of [W2|W3]
    const int t  = threadIdx.x;
    const int rg = t >> 4;           // 0..15 -> rows rg*2, rg*2+1
    const int j  = t & 15;           // k-lane
    const size_t row0 = (size_t)blockIdx.x * 32 + rg * 2;

    float acc0[32], acc1[32];
    #pragma unroll
    for (int n = 0; n < 32; ++n) { acc0[n] = 0.f; acc1[n] = 0.f; }

    for (int kh = 0; kh < 2; ++kh) {
        __syncthreads();
        // stage W half: 512 k-rows x 32 n (bf16), slot-swizzled
        #pragma unroll
        for (int it = 0; it < 16; ++it) {
            const int fidx  = it * 256 + t;       // 0..4095 float4's
            const int which = fidx >> 11;         // 0: W2, 1: W3
            const int sub   = fidx & 2047;
            const int kk    = sub >> 2;           // 0..511
            const int n4    = (sub & 3) << 2;     // 0,4,8,12
            const float* Wsrc = which ? W3 : W2;
            const float4 a = *(const float4*)&Wsrc[(size_t)(kh * 512 + kk) * 16 + n4];
            const int n  = (which << 4) + n4;
            const int sl = (n >> 3) ^ ((kk >> 2) & 3);
            ushort4 u;
            u.x = bf16u(a.x); u.y = bf16u(a.y); u.z = bf16u(a.z); u.w = bf16u(a.w);
            *(ushort4*)((unsigned short*)&Wl[kk][0] + sl * 8 + (n & 7)) = u;
        }
        __syncthreads();

        #pragma unroll 2
        for (int i = 0; i < 8; ++i) {
            const int klocal = i * 64 + (j << 2);
            const int kglob  = (kh << 9) + klocal;
            const float4 xa = *(const float4*)&X[row0 * Dd + kglob];
            const float4 xb = *(const float4*)&X[(row0 + 1) * Dd + kglob];
            ushort4 ua, ub;
            ua.x = bf16u(xa.x); ua.y = bf16u(xa.y); ua.z = bf16u(xa.z); ua.w = bf16u(xa.w);
            ub.x = bf16u(xb.x); ub.y = bf16u(xb.y); ub.z = bf16u(xb.z); ub.w = bf16u(xb.w);
            *(ushort4*)&Xb[row0 * Dd + kglob]       = ua;
            *(ushort4*)&Xb[(row0 + 1) * Dd + kglob] = ub;
            const float* xap = &xa.x;
            const float* xbp = &xb.x;
            #pragma unroll
            for (int di = 0; di < 4; ++di) {
                const int kk = klocal + di;
                const int sw = (kk >> 2) & 3;
                const unsigned short* wrow = (const unsigned short*)&Wl[kk][0];
                const float x0 = xap[di], x1 = xbp[di];
                #pragma unroll
                for (int s = 0; s < 4; ++s) {
                    const uint4 wv = *(const uint4*)(wrow + ((s ^ sw) << 3));
                    const int nb = s << 3;
                    float f;
                    f = bf_lo(wv.x); acc0[nb+0] += x0*f; acc1[nb+0] += x1*f;
                    f = bf_hi(wv.x); acc0[nb+1] += x0*f; acc1[nb+1] += x1*f;
                    f = bf_lo(wv.y); acc0[nb+2] += x0*f; acc1[nb+2] += x1*f;
                    f = bf_hi(wv.y); acc0[nb+3] += x0*f; acc1[nb+3] += x1*f;
                    f = bf_lo(wv.z); acc0[nb+4] += x0*f; acc1[nb+4] += x1*f;
                    f = bf_hi(wv.z); acc0[nb+5] += x0*f; acc1[nb+5] += x1*f;
                    f = bf_lo(wv.w); acc0[nb+6] += x0*f; acc1[nb+6] += x1*f;
                    f = bf_hi(wv.w); acc0[nb+7] += x0*f; acc1[nb+7] += x1*f;
                }
            }
        }
    }

    // reduce over 16 k-lanes (low 4 bits of lane id) via butterfly
    #pragma unroll
    for (int n = 0; n < 32; ++n) {
        float v0 = acc0[n], v1 = acc1[n];
        v0 += __shfl_xor(v0, 1); v0 += __shfl_xor(v0, 2);
        v0 += __shfl_xor(v0, 4); v0 += __shfl_xor(v0, 8);
        v1 += __shfl_xor(v1, 1); v1 += __shfl_xor(v1, 2);
        v1 += __shfl_xor(v1, 4); v1 += __shfl_xor(v1, 8);
        acc0[n] = v0; acc1[n] = v1;
    }
    // lane j selects column j (all lanes hold identical full sums now)
    float B0 = 0.f, C0 = 0.f, B1 = 0.f, C1 = 0.f;
    #pragma unroll
    for (int n = 0; n < 16; ++n) {
        const bool m = (n == j);
        B0 = m ? acc0[n] : B0;  C0 = m ? acc0[n + 16] : C0;
        B1 = m ? acc1[n] : B1;  C1 = m ? acc1[n + 16] : C1;
    }
    const float bb2 = b2[j], bb3 = b3[j];
    float p0 = (B0 + bb2) * (C0 + bb3);
    float p1 = (B1 + bb2) * (C1 + bb3);
    p0 += __shfl_xor(p0, 1); p0 += __shfl_xor(p0, 2);
    p0 += __shfl_xor(p0, 4); p0 += __shfl_xor(p0, 8);
    p1 += __shfl_xor(p1, 1); p1 += __shfl_xor(p1, 2);
    p1 += __shfl_xor(p1, 4); p1 += __shfl_xor(p1, 8);
    if (j == 0) { Sv[row0] = p0; Sv[row0 + 1] = p1; }
}

// ---------------------------------------------------------------------------
// Kernel 2: W1 [k][n] fp32 -> W1t [n][k] bf16 (64x64 tiles, padded LDS)
// ---------------------------------------------------------------------------
__global__ __launch_bounds__(256) void prep_w1_kernel(
    const float* __restrict__ W1, __bf16* __restrict__ W1t)
{
    __shared__ __bf16 tile[64][66];
    const int t  = threadIdx.x;
    const int bi = blockIdx.x >> 4;   // k tile
    const int bj = blockIdx.x & 15;   // n tile
    const int c  = t & 63, r4 = t >> 6;
    #pragma unroll
    for (int i = 0; i < 16; ++i) {
        const int r = i * 4 + r4;
        tile[r][c] = (__bf16)W1[(size_t)(bi * 64 + r) * Dd + bj * 64 + c];
    }
    __syncthreads();
    #pragma unroll
    for (int i = 0; i < 16; ++i) {
        const int r = i * 4 + r4;
        W1t[(size_t)(bj * 64 + r) * Dd + bi * 64 + c] = tile[c][r];
    }
}

// ---------------------------------------------------------------------------
// Kernel 3: bf16 MFMA GEMM, 128x128 tile, BK=32, XOR-swizzled LDS slots
// (conflict-free frag reads), fused epilogue y = xb * softplus(g+b1) * s[row].
// ---------------------------------------------------------------------------
__global__ __launch_bounds__(256, 2) void gemm_kernel(
    const __bf16* __restrict__ Xb, const __bf16* __restrict__ W1t,
    const float* __restrict__ Sv, const float* __restrict__ b1,
    float* __restrict__ Y)
{
    __shared__ __attribute__((aligned(16))) __bf16 lds[8192]; // A: [0,4096) B: [4096,8192)
    const int t    = threadIdx.x;
    const int lane = t & 63;
    const int w    = t >> 6;
    const int wm   = w & 1, wn = w >> 1;
    const int cb   = blockIdx.x & 7, rb = blockIdx.x >> 3;  // cb tied to XCD for W1t L2 reuse
    const int row0 = rb * 128, col0 = cb * 128;
    const int quad = lane >> 4, l15 = lane & 15;

    floatx4 acc[4][4] = {};

    // swizzled staging: 16B slot u holds (rowL, chunk) with c4 = (u&7) ^ ((u>>3)&7)
    const __bf16* gA[2]; const __bf16* gB[2];
    int dA[2], dB[2];
    #pragma unroll
    for (int r = 0; r < 2; ++r) {
        const int u = r * 256 + t;
        const int p = u >> 3, s = u & 7, c4 = s ^ (p & 7);
        const int rowL = 2 * p + (c4 >> 2), chk = c4 & 3;
        gA[r] = Xb  + (size_t)(row0 + rowL) * Dd + chk * 8;
        gB[r] = W1t + (size_t)(col0 + rowL) * Dd + chk * 8;
        dA[r] = u * 8;
        dB[r] = 4096 + u * 8;
    }

    for (int k0 = 0; k0 < Dd; k0 += 32) {
        #pragma unroll
        for (int r = 0; r < 2; ++r) {
            __builtin_amdgcn_global_load_lds(GLB(gA[r] + k0), LDSP(&lds[dA[r]]), 16, 0, 0);
            __builtin_amdgcn_global_load_lds(GLB(gB[r] + k0), LDSP(&lds[dB[r]]), 16, 0, 0);
        }
        __syncthreads();

        bf16x8 af[4], bfr[4];
        #pragma unroll
        for (int mt = 0; mt < 4; ++mt) {
            const int rl = wm * 64 + mt * 16 + l15;
            const int p = rl >> 1, c4 = ((rl & 1) << 2) | quad, s = c4 ^ (p & 7);
            af[mt] = *(const bf16x8*)&lds[p * 64 + s * 8];
        }
        #pragma unroll
        for (int nt = 0; nt < 4; ++nt) {
            const int nl = wn * 64 + nt * 16 + l15;
            const int p = nl >> 1, c4 = ((nl & 1) << 2) | quad, s = c4 ^ (p & 7);
            bfr[nt] = *(const bf16x8*)&lds[4096 + p * 64 + s * 8];
        }
        #pragma unroll
        for (int mt = 0; mt < 4; ++mt)
            #pragma unroll
            for (int nt = 0; nt < 4; ++nt)
                acc[mt][nt] = __builtin_amdgcn_mfma_f32_16x16x32_bf16(
                    af[mt], bfr[nt], acc[mt][nt], 0, 0, 0);
        __syncthreads();
    }

    // epilogue: C/D layout col = l15, row = quad*4 + rr
    float bias[4];
    #pragma unroll
    for (int nt = 0; nt < 4; ++nt) bias[nt] = b1[col0 + wn * 64 + nt * 16 + l15];

    #pragma unroll
    for (int mt = 0; mt < 4; ++mt) {
        #pragma unroll
        for (int rr = 0; rr < 4; ++rr) {
            const int row = row0 + wm * 64 + mt * 16 + quad * 4 + rr;
            const float sv = Sv[row];
            const unsigned short* xrow = (const unsigned short*)(Xb + (size_t)row * Dd + col0);
            float* yrow = Y + (size_t)row * Dd + col0;
            #pragma unroll
            for (int nt = 0; nt < 4; ++nt) {
                const int cl = wn * 64 + nt * 16 + l15;
                const float v  = acc[mt][nt][rr] + bias[nt];
                const float sp = softplus_fast(v);
                const float xv = bf_lo((unsigned)xrow[cl]);
                yrow[cl] = xv * sp * sv;
            }
        }
    }
}

} // namespace

extern "C" void kernel_launch(void* const* d_in, const int* in_sizes, int n_in,
                              void* d_out, int out_size, void* d_ws, size_t ws_size,
                              hipStream_t stream)
{
    const float* X  = (const float*)d_in[0];
    const float* W1 = (const float*)d_in[1];
    const float* b1 = (const float*)d_in[2];
    const float* W2 = (const float*)d_in[3];
    const float* b2 = (const float*)d_in[4];
    const float* W3 = (const float*)d_in[5];
    const float* b3 = (const float*)d_in[6];
    // d_in[7] = A is dead code in the reference.
    float* Y = (float*)d_out;

    // workspace: Xb (16 MB bf16) | W1t (2 MB bf16) | Sv (32 KB fp32)
    __bf16* Xb  = (__bf16*)d_ws;
    __bf16* W1t = (__bf16*)((char*)d_ws + (size_t)ROWS * Dd * 2);
    float*  Sv  = (float*)((char*)d_ws + (size_t)ROWS * Dd * 2 + (size_t)Dd * Dd * 2);

    hipLaunchKernelGGL(prep_x_kernel, dim3(ROWS / 32), dim3(256), 0, stream,
                       X, W2, b2, W3, b3, Xb, Sv);
    hipLaunchKernelGGL(prep_w1_kernel, dim3(256), dim3(256), 0, stream, W1, W1t);
    hipLaunchKernelGGL(gemm_kernel, dim3((ROWS / 128) * (Dd / 128)), dim3(256), 0, stream,
                       Xb, W1t, Sv, b1, Y);
}